// Round 9
// baseline (1134.030 us; speedup 1.0000x reference)
//
#include <hip/hip_runtime.h>
#include <math.h>

// FactorizationMachine: out = sigmoid( X@fc_w + fc_b + 0.5*( sum_d (X@w)_d^2 - (X^2)@g ) ),
// g[f] = sum_d w[f,d]^2 inline.
//
// R8 model (fits R0-R7): dur ~ per-CU unique bytes / HBM-share; W's logical
// traffic (3.2 MB x blocks sweeping it) misses cache because streaming X
// flushes L2 (~5 us) and LLC (~40 us) vs W re-touch ~300 us. Lever: rows/block.
//  - 1024-thr block = 16 waves x 4 rows = 64 rows/block -> W logical 205 MB
//    (vs R0 1.64 GB) even at 100% miss. All waves sweep the SAME f4 window
//    (phase-aligned, lane-stride-64) for disjoint rows -> W also L1/L2-shared.
//  - 68 acc + 16 xv + 16 wv + fw ~ 110 VGPR, __launch_bounds__(1024,4)
//    -> 16 waves/CU. No LDS in main loop, no barriers, no runtime reg-indexing.
//  - KSPLIT=4 -> 256 blocks (1/CU); partials to ws; phase-2 combine + sigmoid.

constexpr int B_ROWS  = 4096;
constexpr int F_FEAT  = 50000;
constexpr int NF4     = F_FEAT / 4;          // 12500
constexpr int D_FAC   = 16;
constexpr int TPB     = 1024;
constexpr int WAVES   = TPB / 64;            // 16
constexpr int RW      = 4;                   // rows per wave
constexpr int RB      = WAVES * RW;          // 64 rows per block
constexpr int NGRP    = B_ROWS / RB;         // 64 row-groups
constexpr int KSPLIT  = 4;
constexpr int CHUNK   = NF4 / KSPLIT;        // 3125
constexpr int NBLK    = NGRP * KSPLIT;       // 256 blocks (1 per CU)
constexpr int PV      = RW * (D_FAC + 1);    // 68 partials per wave

typedef float f32x4 __attribute__((ext_vector_type(4)));

// ---------------- Phase 1: main sweep ----------------
__global__ __launch_bounds__(TPB, 4)
void fm_main(const float* __restrict__ X,
             const float* __restrict__ fcw,
             const float* __restrict__ W,
             float* __restrict__ pout)        // ws
{
    const int tid  = threadIdx.x;
    const int lane = tid & 63;
    const int wid  = tid >> 6;               // 0..15, wave-uniform
    const int c    = blockIdx.x & (KSPLIT - 1);
    const int grp  = blockIdx.x >> 2;
    const int row0 = grp * RB + wid * RW;
    const int beg  = c * CHUNK;
    const int end  = beg + CHUNK;

    const f32x4* X4  = reinterpret_cast<const f32x4*>(X);
    const f32x4* W4  = reinterpret_cast<const f32x4*>(W);
    const f32x4* FW4 = reinterpret_cast<const f32x4*>(fcw);

    float s[RW][D_FAC];                      // 64 acc
    float lin[RW];                           // 4 (linear + sum_sq-correction fused)
#pragma unroll
    for (int r = 0; r < RW; ++r) {
        lin[r] = 0.f;
#pragma unroll
        for (int t = 0; t < D_FAC; ++t) s[r][t] = 0.f;
    }

    // All 16 waves use the SAME f4 each iteration (W shared via L1/L2);
    // each wave applies it to its own 4 rows.
    for (int f4 = beg + lane; f4 < end; f4 += 64) {
        f32x4 xv[RW];                        // this wave's 4 X streams, coalesced
#pragma unroll
        for (int r = 0; r < RW; ++r)
            xv[r] = X4[(size_t)(row0 + r) * NF4 + f4];

        const f32x4 fw = FW4[f4];

#pragma unroll
        for (int j = 0; j < 4; ++j) {        // 4 features of the float4 group
            f32x4 wv[4];                     // w row of feature j (16 floats)
#pragma unroll
            for (int q = 0; q < 4; ++q)
                wv[q] = W4[(size_t)f4 * 16 + 4 * j + q];

            float gp = 0.f;                  // -0.5 * sum_d w^2
#pragma unroll
            for (int t = 0; t < D_FAC; ++t) {
                const float wd = wv[t >> 2][t & 3];
                gp = fmaf(wd, wd, gp);
            }
            gp *= -0.5f;

            const float fwj = fw[j];
#pragma unroll
            for (int r = 0; r < RW; ++r) {
                const float x  = xv[r][j];
                const float x2 = x * x;
                lin[r] = fmaf(x, fwj, lin[r]);
                lin[r] = fmaf(x2, gp, lin[r]);
#pragma unroll
                for (int t = 0; t < D_FAC; ++t)
                    s[r][t] = fmaf(x, wv[t >> 2][t & 3], s[r][t]);
            }
        }
    }

    // ---- per-wave butterfly reduce of 68 values; value i -> lane i&63, reg i>>6 ----
    float keep0 = 0.f, keep1 = 0.f;
    int idx = 0;
#pragma unroll
    for (int r = 0; r < RW; ++r) {
#pragma unroll
        for (int t = 0; t <= D_FAC; ++t) {
            float v = (t < D_FAC) ? s[r][t] : lin[r];
#pragma unroll
            for (int m = 32; m >= 1; m >>= 1) v += __shfl_xor(v, m, 64);
            if (idx < 64) { if (lane == idx) keep0 = v; }
            else          { if (lane == idx - 64) keep1 = v; }
            ++idx;
        }
    }
    float* base = pout + ((size_t)blockIdx.x * WAVES + wid) * PV;
    base[lane] = keep0;                      // 64 coalesced
    if (lane < PV - 64) base[64 + lane] = keep1;
}

// ---------------- Phase 2: combine chunks + sigmoid ----------------
__global__ __launch_bounds__(256)
void fm_final(const float* __restrict__ pout,
              const float* __restrict__ fcb,
              float* __restrict__ out)
{
    const int r = blockIdx.x * 256 + threadIdx.x;
    if (r >= B_ROWS) return;
    const int grp = r >> 6;                  // row-group of 64
    const int rr  = r & 63;
    const int wid = rr >> 2;                 // wave within block
    const int rw  = rr & 3;                  // row within wave

    float acc[D_FAC + 1];
#pragma unroll
    for (int t = 0; t <= D_FAC; ++t) acc[t] = 0.f;

#pragma unroll
    for (int c = 0; c < KSPLIT; ++c) {
        const float* p = pout
            + ((size_t)((grp * KSPLIT + c) * WAVES + wid)) * PV + rw * (D_FAC + 1);
#pragma unroll
        for (int t = 0; t <= D_FAC; ++t) acc[t] += p[t];
    }

    float ss = 0.f;
#pragma unroll
    for (int t = 0; t < D_FAC; ++t) ss = fmaf(acc[t], acc[t], ss);

    const float logit = acc[D_FAC] + fcb[0] + 0.5f * ss;
    out[r] = 1.0f / (1.0f + expf(-logit));
}

extern "C" void kernel_launch(void* const* d_in, const int* in_sizes, int n_in,
                              void* d_out, int out_size, void* d_ws, size_t ws_size,
                              hipStream_t stream)
{
    const float* X   = (const float*)d_in[0];
    const float* fcw = (const float*)d_in[1];
    const float* fcb = (const float*)d_in[2];
    const float* W   = (const float*)d_in[3];
    float* out = (float*)d_out;
    float* ws  = (float*)d_ws;   // needs 256*16*68*4 B = 1.11 MB

    hipLaunchKernelGGL(fm_main, dim3(NBLK), dim3(TPB), 0, stream, X, fcw, W, ws);
    hipLaunchKernelGGL(fm_final, dim3((B_ROWS + 255) / 256), dim3(256), 0, stream,
                       ws, fcb, out);
}

// Round 10
// 293.112 us; speedup vs baseline: 3.8689x; 3.8689x over previous
//
#include <hip/hip_runtime.h>
#include <math.h>

// FactorizationMachine: out = sigmoid( X@fc_w + fc_b + 0.5*( sum_d (X@w)_d^2 - (X^2)@g ) ),
// g[f] = sum_d w[f,d]^2 inline.
//
// R9 = combine the two PROVEN halves:
//  - R8 proved 64 rows/block -> HBM fetch = ideal (836 MB measured; W absorbed
//    by L2/LLC). Its failure was VGPR=64 (compiler squeeze) -> no load hoisting
//    -> latency-bound at 0.7 TB/s effective.
//  - R0/R4 proved the hoisted-load schedule (8 xv + batched wv + fw in regs,
//    ~250 VGPR, few waves) saturates HBM at 6.4 TB/s.
// Design: 512-thr block = 8 waves x 8 rows = 64 rows/block; each wave = R4's
// exact inner loop (two-batch wv keeps regs ~210; launch_bounds(512,2) caps 256
// -> 2 waves/SIMD, one block/CU). KSPLIT=4 -> 256 blocks = 1/CU, no tail.
// W chunk c touches only XCDs {c,4+c} mod 8 -> W HBM fetch ~6 MB.
// Phase 2 combines 4 chunk-partials/row + sigmoid (validated absmax<=2e-9).

constexpr int B_ROWS  = 4096;
constexpr int F_FEAT  = 50000;
constexpr int NF4     = F_FEAT / 4;        // 12500
constexpr int D_FAC   = 16;
constexpr int TPB     = 512;
constexpr int WPB     = 8;                 // waves per block
constexpr int ROWS    = 8;                 // rows per wave
constexpr int RB      = WPB * ROWS;        // 64 rows per block
constexpr int NGRP    = B_ROWS / RB;       // 64 row-groups
constexpr int KSPLIT  = 4;
constexpr int CHUNK   = NF4 / KSPLIT;      // 3125
constexpr int NBLK    = NGRP * KSPLIT;     // 256 blocks (1 per CU)
constexpr int NVAL    = ROWS * (D_FAC + 1);// 136 partials per wave

typedef float f32x4 __attribute__((ext_vector_type(4)));

// ---------------- Phase 1: main sweep ----------------
__global__ __launch_bounds__(TPB, 2)   // cap 256 VGPR; 8 waves/CU (one block)
void fm_main(const float* __restrict__ X,
             const float* __restrict__ fcw,
             const float* __restrict__ W,
             float* __restrict__ pout)     // ws
{
    const int tid  = threadIdx.x;
    const int lane = tid & 63;
    const int wid  = tid >> 6;             // 0..7, wave-uniform
    const int c    = blockIdx.x & (KSPLIT - 1);
    const int grp  = blockIdx.x >> 2;
    const int row0 = grp * RB + wid * ROWS;
    const int beg  = c * CHUNK;
    const int end  = beg + CHUNK;

    const f32x4* X4  = reinterpret_cast<const f32x4*>(X);
    const f32x4* W4  = reinterpret_cast<const f32x4*>(W);
    const f32x4* FW4 = reinterpret_cast<const f32x4*>(fcw);

    float s[ROWS][D_FAC];                  // 128 acc
    float lin[ROWS];                       // 8  (linear + sum_sq correction fused)
#pragma unroll
    for (int r = 0; r < ROWS; ++r) {
        lin[r] = 0.f;
#pragma unroll
        for (int t = 0; t < D_FAC; ++t) s[r][t] = 0.f;
    }

    // All 8 waves sweep the SAME f4 cadence (W shared via L1/L2), each for its
    // own 8 rows. R4's hoisted schedule: 8 xv up front, wv in two 8-reg batches.
    for (int f4 = beg + lane; f4 < end; f4 += 64) {
        f32x4 xv[ROWS];                    // 8 coalesced X streams
#pragma unroll
        for (int r = 0; r < ROWS; ++r)
            xv[r] = X4[(size_t)(row0 + r) * NF4 + f4];

        const f32x4 fw = FW4[f4];

        // W batch 1: features j=0,1 (8 f32x4, reused registers)
        f32x4 wv[8];
#pragma unroll
        for (int q = 0; q < 8; ++q)
            wv[q] = W4[(size_t)f4 * 16 + q];

#pragma unroll
        for (int j = 0; j < 2; ++j) {
            float wd[D_FAC];
#pragma unroll
            for (int t = 0; t < D_FAC; ++t)
                wd[t] = wv[4 * j + (t >> 2)][t & 3];

            float gp = 0.f;
#pragma unroll
            for (int t = 0; t < D_FAC; ++t) gp = fmaf(wd[t], wd[t], gp);
            gp *= -0.5f;

            const float fwj = fw[j];
#pragma unroll
            for (int r = 0; r < ROWS; ++r) {
                const float x  = xv[r][j];
                const float x2 = x * x;
                lin[r] = fmaf(x, fwj, lin[r]);
                lin[r] = fmaf(x2, gp, lin[r]);
#pragma unroll
                for (int t = 0; t < D_FAC; ++t)
                    s[r][t] = fmaf(x, wd[t], s[r][t]);
            }
        }

        // W batch 2: features j=2,3 (same 8 registers)
#pragma unroll
        for (int q = 0; q < 8; ++q)
            wv[q] = W4[(size_t)f4 * 16 + 8 + q];

#pragma unroll
        for (int j = 0; j < 2; ++j) {
            const int jj = j + 2;
            float wd[D_FAC];
#pragma unroll
            for (int t = 0; t < D_FAC; ++t)
                wd[t] = wv[4 * j + (t >> 2)][t & 3];

            float gp = 0.f;
#pragma unroll
            for (int t = 0; t < D_FAC; ++t) gp = fmaf(wd[t], wd[t], gp);
            gp *= -0.5f;

            const float fwj = fw[jj];
#pragma unroll
            for (int r = 0; r < ROWS; ++r) {
                const float x  = xv[r][jj];
                const float x2 = x * x;
                lin[r] = fmaf(x, fwj, lin[r]);
                lin[r] = fmaf(x2, gp, lin[r]);
#pragma unroll
                for (int t = 0; t < D_FAC; ++t)
                    s[r][t] = fmaf(x, wd[t], s[r][t]);
            }
        }
    }

    // ---- per-wave butterfly reduce of 136 values; value i -> lane i&63 ----
    float keep0 = 0.f, keep1 = 0.f, keep2 = 0.f;
    int idx = 0;
#pragma unroll
    for (int r = 0; r < ROWS; ++r) {
#pragma unroll
        for (int t = 0; t <= D_FAC; ++t) {
            float v = (t < D_FAC) ? s[r][t] : lin[r];
#pragma unroll
            for (int m = 32; m >= 1; m >>= 1) v += __shfl_xor(v, m, 64);
            if (idx < 64)       { if (lane == idx)        keep0 = v; }
            else if (idx < 128) { if (lane == idx - 64)   keep1 = v; }
            else                { if (lane == idx - 128)  keep2 = v; }
            ++idx;
        }
    }
    float* base = pout + ((size_t)blockIdx.x * WPB + wid) * NVAL;
    base[lane] = keep0;
    base[64 + lane] = keep1;
    if (lane < NVAL - 128) base[128 + lane] = keep2;
}

// ---------------- Phase 2: combine chunks + sigmoid ----------------
__global__ __launch_bounds__(256)
void fm_final(const float* __restrict__ pout,
              const float* __restrict__ fcb,
              float* __restrict__ out)
{
    const int r = blockIdx.x * 256 + threadIdx.x;
    if (r >= B_ROWS) return;
    const int grp = r >> 6;                // row-group of 64
    const int rr  = r & 63;
    const int wid = rr >> 3;               // wave within block
    const int rw  = rr & 7;                // row within wave

    float acc[D_FAC + 1];
#pragma unroll
    for (int t = 0; t <= D_FAC; ++t) acc[t] = 0.f;

#pragma unroll
    for (int c = 0; c < KSPLIT; ++c) {
        const float* p = pout
            + ((size_t)((grp * KSPLIT + c) * WPB + wid)) * NVAL + rw * (D_FAC + 1);
#pragma unroll
        for (int t = 0; t <= D_FAC; ++t) acc[t] += p[t];
    }

    float ss = 0.f;
#pragma unroll
    for (int t = 0; t < D_FAC; ++t) ss = fmaf(acc[t], acc[t], ss);

    const float logit = acc[D_FAC] + fcb[0] + 0.5f * ss;
    out[r] = 1.0f / (1.0f + expf(-logit));
}

extern "C" void kernel_launch(void* const* d_in, const int* in_sizes, int n_in,
                              void* d_out, int out_size, void* d_ws, size_t ws_size,
                              hipStream_t stream)
{
    const float* X   = (const float*)d_in[0];
    const float* fcw = (const float*)d_in[1];
    const float* fcb = (const float*)d_in[2];
    const float* W   = (const float*)d_in[3];
    float* out = (float*)d_out;
    float* ws  = (float*)d_ws;   // needs 256*8*136*4 B = 1.11 MB

    hipLaunchKernelGGL(fm_main, dim3(NBLK), dim3(TPB), 0, stream, X, fcw, W, ws);
    hipLaunchKernelGGL(fm_final, dim3((B_ROWS + 255) / 256), dim3(256), 0, stream,
                       ws, fcb, out);
}